// Round 7
// baseline (436.525 us; speedup 1.0000x reference)
//
#include <hip/hip_runtime.h>

typedef _Float16 f16;
typedef _Float16 half2v __attribute__((ext_vector_type(2)));
typedef _Float16 half4v __attribute__((ext_vector_type(4)));
typedef _Float16 half8 __attribute__((ext_vector_type(8)));
typedef float f32x4 __attribute__((ext_vector_type(4)));

#define MFMA16(a, b, c) __builtin_amdgcn_mfma_f32_16x16x32_f16((a), (b), (c), 0, 0, 0)

// Sizes: B=4, CI=64, H=W=128 ; conv out 64x64 ; C=160 ; S=4097 ; SQ=4096 ; NH=4 ; HD=40
// q layout: [bh(16)][s(4097)][40] f16 packed (no d-pad; MFMA k 40..63 fed from LDS zero blk)
// k layout: [bh(16)][s(4160)][40] f16 packed (rows 4097.. uninit, masked on last tile)
// vt layout: [bh(16)][d(40)][4160] f16
// pacc: [ks(2)][bh(16)][q(4096)][48] f32 partial o; col 40 = partial l (ones-column trick)
// Softmax: P = exp2(s*scale*log2e - mfix), mfix = |q|*maxK*scale*log2e - 14 (Cauchy-Schwarz
// bound; Delta=14 keeps f16 P out of subnormals, P <= 2^14 < 65504). Fixed shift => K-split
// partials combine linearly: o = o0+o1, l = l0+l1.

// ---------------- K0: prep (w2 transpose, f pad row, maxk2 init) ----------------
__global__ __launch_bounds__(256) void k_prep(
    const float* __restrict__ w2, const float* __restrict__ pe,
    float* __restrict__ w2t, f16* __restrict__ f_h, int* __restrict__ maxk2) {
  int i = blockIdx.x * 256 + threadIdx.x;
  if (i < 10240) {                       // w2t[co][c2] = w2[c2][co]
    int co = i / 160, c2 = i - co * 160;
    w2t[co * 160 + c2] = w2[c2 * 64 + co];
  } else if (i < 10880) {                // f[b][4096][c] = pe[4096]
    int j = i - 10240;
    int bb = j / 160, c = j - bb * 160;
    f_h[(bb * 4097 + 4096) * 160 + c] = (f16)pe[4096];
  } else if (i < 10896) {                // maxk2 init (0 as int == 0.0f; sums are > 0)
    maxk2[i - 10880] = 0;
  }
}

// ---------------- K1: conv1(2x2 s2) + b1 + conv2(1x1) + b2 + leaky + pe -> f fp16 -------
__global__ __launch_bounds__(256) void k_conv(
    const float* __restrict__ x, const float* __restrict__ w1, const float* __restrict__ b1,
    const float* __restrict__ w2t, const float* __restrict__ b2, const float* __restrict__ pe,
    f16* __restrict__ f_h) {
  __shared__ float xin[32 * 4 * 64];
  __shared__ float c1[64 * 64];
  int y = blockIdx.x, b = blockIdx.y;
  int t = threadIdx.x, lane = t & 63, wv = t >> 6;
  const float* xb = x + (b * 64) * 16384 + (2 * y) * 128;

  int cob = __builtin_amdgcn_readfirstlane(wv * 16);
  float acc[16];
#pragma unroll
  for (int j = 0; j < 16; ++j) acc[j] = b1[cob + j];

  for (int half = 0; half < 2; ++half) {
    __syncthreads();
    for (int k = 0; k < 32; ++k) {
      int i = t + (k << 8);
      int cil = i >> 8, rem = i & 255, r = rem >> 7, col = rem & 127;
      xin[(cil * 4 + r * 2 + (col & 1)) * 64 + (col >> 1)] =
          xb[(half * 32 + cil) * 16384 + r * 128 + col];
    }
    __syncthreads();
    for (int cil = 0; cil < 32; ++cil) {
      int ci = half * 32 + cil;
      float x00 = xin[(cil * 4 + 0) * 64 + lane];
      float x01 = xin[(cil * 4 + 1) * 64 + lane];
      float x10 = xin[(cil * 4 + 2) * 64 + lane];
      float x11 = xin[(cil * 4 + 3) * 64 + lane];
      const float* wr = w1 + (cob * 64 + ci) * 4;
#pragma unroll
      for (int j = 0; j < 16; ++j) {
        acc[j] += wr[j * 256 + 0] * x00 + wr[j * 256 + 1] * x01 +
                  wr[j * 256 + 2] * x10 + wr[j * 256 + 3] * x11;
      }
    }
  }
#pragma unroll
  for (int j = 0; j < 16; ++j) c1[(cob + j) * 64 + lane] = acc[j];
  __syncthreads();

  int c2b = __builtin_amdgcn_readfirstlane(wv * 40);
  float a2[40];
#pragma unroll
  for (int j = 0; j < 40; ++j) a2[j] = b2[c2b + j];
  for (int co = 0; co < 64; ++co) {
    float xv = c1[co * 64 + lane];
    const float* wr = w2t + co * 160 + c2b;
#pragma unroll
    for (int j = 0; j < 40; ++j) a2[j] += xv * wr[j];
  }
  int s = y * 64 + lane;
  float pes = pe[s];
  f16* dst = f_h + (b * 4097 + s) * 160 + c2b;
#pragma unroll
  for (int j = 0; j < 40; ++j) {
    float v = a2[j];
    v = (v >= 0.f) ? v : 0.01f * v;
    v += pes;
    dst[j] = (f16)v;
  }
}

// ---------------- K2: QKV gemms via MFMA (f32 weights converted during staging) ---------
__global__ __launch_bounds__(256) void k_qkv(
    const f16* __restrict__ f_h,
    const float* __restrict__ wq, const float* __restrict__ wk, const float* __restrict__ wv,
    f16* __restrict__ q_h, f16* __restrict__ k_h, f16* __restrict__ vt_h) {
  __shared__ __attribute__((aligned(16))) f16 fT[64 * 168];
  __shared__ __attribute__((aligned(16))) f16 wT[80 * 168];
  int sb = blockIdx.x, b = blockIdx.y;
  int s0 = sb * 64;
  int t = threadIdx.x, lane = t & 63, wv2 = t >> 6, quad = lane >> 4, col = lane & 15;

  for (int c = t; c < 1280; c += 256) {
    int row = c / 20, seg = c - row * 20;
    int srow = s0 + row; if (srow > 4096) srow = 4096;
    *(uint4*)(fT + row * 168 + seg * 8) =
        *(const uint4*)(f_h + (b * 4097 + srow) * 160 + seg * 8);
  }
  __syncthreads();
  half8 af[5];
  int rowA = wv2 * 16 + col;
#pragma unroll
  for (int kk = 0; kk < 5; ++kk)
    af[kk] = *(half8*)(fT + rowA * 168 + kk * 32 + quad * 8);

  for (int kind = 0; kind < 3; ++kind) {
    const float* wsp = (kind == 0) ? wq : (kind == 1 ? wk : wv);
    for (int hf = 0; hf < 2; ++hf) {
      __syncthreads();
      for (int c = t; c < 1600; c += 256) {
        int row = c / 20, seg = c - row * 20;
        const float* src = wsp + (hf * 80 + row) * 160 + seg * 8;
        f32x4 va = *(const f32x4*)src;
        f32x4 vb = *(const f32x4*)(src + 4);
        uint4 u;
        u.x = __builtin_bit_cast(unsigned, __builtin_amdgcn_cvt_pkrtz(va[0], va[1]));
        u.y = __builtin_bit_cast(unsigned, __builtin_amdgcn_cvt_pkrtz(va[2], va[3]));
        u.z = __builtin_bit_cast(unsigned, __builtin_amdgcn_cvt_pkrtz(vb[0], vb[1]));
        u.w = __builtin_bit_cast(unsigned, __builtin_amdgcn_cvt_pkrtz(vb[2], vb[3]));
        *(uint4*)(wT + row * 168 + seg * 8) = u;
      }
      __syncthreads();
#pragma unroll
      for (int n0 = 0; n0 < 5; ++n0) {
        f32x4 acc; acc[0] = 0.f; acc[1] = 0.f; acc[2] = 0.f; acc[3] = 0.f;
        int rowB = n0 * 16 + col;
#pragma unroll
        for (int kk = 0; kk < 5; ++kk) {
          half8 bf = *(half8*)(wT + rowB * 168 + kk * 32 + quad * 8);
          acc = MFMA16(af[kk], bf, acc);
        }
        int o = (hf * 5 + n0) * 16 + col;
        int hh = o / 40, d = o - hh * 40;
        int bh = b * 4 + hh;
#pragma unroll
        for (int r = 0; r < 4; ++r) {
          int s = s0 + wv2 * 16 + quad * 4 + r;
          if (s <= 4096) {
            f16 v = (f16)acc[r];
            if (kind == 0)      q_h[((size_t)bh * 4097 + s) * 40 + d] = v;
            else if (kind == 1) k_h[((size_t)bh * 4160 + s) * 40 + d] = v;
            else                vt_h[((size_t)bh * 40 + d) * 4160 + s] = v;
          }
        }
      }
    }
  }
}

// ---------------- K2b: per-head max ||k||^2 (packed stride 40) ----------------
__global__ __launch_bounds__(256) void k_norm1(const f16* __restrict__ k_h,
                                               int* __restrict__ maxk2) {
  int bh = blockIdx.x >> 3, chunk = blockIdx.x & 7;
  int t = threadIdx.x;
  int lo = chunk * 513, hi = lo + 513; if (hi > 4097) hi = 4097;
  float mx = 0.f;
  for (int i = lo + t; i < hi; i += 256) {
    const f16* kr = k_h + ((size_t)bh * 4160 + i) * 40;
    float s = 0.f;
#pragma unroll
    for (int c = 0; c < 5; ++c) {
      half8 v = *(const half8*)(kr + c * 8);
#pragma unroll
      for (int j = 0; j < 8; ++j) { float f = (float)v[j]; s += f * f; }
    }
    mx = fmaxf(mx, s);
  }
#pragma unroll
  for (int d = 1; d < 64; d <<= 1) mx = fmaxf(mx, __shfl_xor(mx, d));
  __shared__ float red[4];
  if ((t & 63) == 0) red[t >> 6] = mx;
  __syncthreads();
  if (t == 0) {
    float m = fmaxf(fmaxf(red[0], red[1]), fmaxf(red[2], red[3]));
    atomicMax(maxk2 + bh, __float_as_int(m));
  }
}

// V B-fragment loader for one 64-key tile: lane (col,quad) supplies
// B[k=kk2*32+quad*8+j][n=nv*16+col]; d>=40 rows are ones (d==40, the l-column) / zeros.
__device__ __forceinline__ void load_v_frags(const f16* __restrict__ vt_h, int bh, int k0,
                                             int col, int quad, uint4 (&bv)[3][2]) {
  const uint4 vones = {0x3C003C00u, 0x3C003C00u, 0x3C003C00u, 0x3C003C00u};
  const uint4 vzero = {0u, 0u, 0u, 0u};
#pragma unroll
  for (int nv = 0; nv < 3; ++nv) {
    int d = nv * 16 + col;
#pragma unroll
    for (int kk2 = 0; kk2 < 2; ++kk2) {
      if (d < 40)
        bv[nv][kk2] =
            *(const uint4*)(vt_h + ((size_t)bh * 40 + d) * 4160 + k0 + kk2 * 32 + quad * 8);
      else
        bv[nv][kk2] = (d == 40) ? vones : vzero;
    }
  }
}

// ---------------- K3: flash attention, K-split x2, packed d40, V reg-dbuf ----------------
// grid (32 qt, 16 bh, 2 ks). 4 waves x 32 q = 128 q/block. One barrier/iter (K LDS dbuf).
// K tile AND V fragments are prefetched one full iteration ahead (R6 regression root cause:
// same-iteration V loads exposed L2-miss latency right after the barrier).
__global__ __launch_bounds__(256, 4) void k_attn(
    const f16* __restrict__ q_h, const f16* __restrict__ k_h,
    const f16* __restrict__ vt_h, const int* __restrict__ maxk2,
    float* __restrict__ pacc) {
  __shared__ __attribute__((aligned(16))) f16 Ks[2][64 * 40];  // packed flat K tile, dbuf
  __shared__ __attribute__((aligned(16))) f16 Zro[8];          // shared zero blk (k 40..63)
  __shared__ __attribute__((aligned(16))) f16 Ps[4 * 32 * 72]; // per-wave P; doubles as Q stage

  int qt = blockIdx.x, bh = blockIdx.y, ks = blockIdx.z;
  int qbase = qt * 128;
  int t = threadIdx.x, lane = t & 63, wv = t >> 6, quad = lane >> 4, col = lane & 15;
  const float c1l = 0.15811388300841898f * 1.4426950408889634f;  // scale*log2e
  int gbase = ks * 33;
  int nIter = 33 - ks;  // 33 / 32 tiles

  // ---- stage Q packed [128][40] into Ps; zero blk ----
  const f16* qb = q_h + ((size_t)bh * 4097 + qbase) * 40;
  for (int c = t; c < 640; c += 256)
    *(uint4*)(Ps + c * 8) = *(const uint4*)(qb + c * 8);
  if (t < 8) Zro[t] = (f16)0;

  // ---- tile 0: K regs + V frags prefetch ----
  const f16* khb = k_h + ((size_t)bh * 4160 + gbase * 64) * 40;
  uint4 rka = *(const uint4*)(khb + t * 8);
  uint4 rkb = {0, 0, 0, 0};
  if (t < 64) rkb = *(const uint4*)(khb + (256 + t) * 8);
  uint4 bvc[3][2];
  load_v_frags(vt_h, bh, gbase << 6, col, quad, bvc);
  __syncthreads();

  // ---- Q fragments + per-row mfix (fused k_norm2) ----
  half8 bq[2][2];
  float mfl[2];
  float mk = __int_as_float(maxk2[bh]);
#pragma unroll
  for (int nt = 0; nt < 2; ++nt) {
    int row = wv * 32 + nt * 16 + col;
    bq[nt][0] = *(half8*)(Ps + row * 40 + quad * 8);
    const f16* p1 = (quad == 0) ? (Ps + row * 40 + 32) : Zro;
    bq[nt][1] = *(half8*)p1;
    float s = 0.f;
#pragma unroll
    for (int j = 0; j < 8; ++j) {
      float a0 = (float)bq[nt][0][j], a1 = (float)bq[nt][1][j];
      s += a0 * a0 + a1 * a1;
    }
    s += __shfl_xor(s, 16);
    s += __shfl_xor(s, 32);
    mfl[nt] = sqrtf(s * mk) * c1l - 14.0f;  // Delta=14 anti-subnormal boost
  }

  f32x4 o_[2][3];
#pragma unroll
  for (int a = 0; a < 2; ++a)
#pragma unroll
    for (int b2 = 0; b2 < 3; ++b2)
#pragma unroll
      for (int r = 0; r < 4; ++r) o_[a][b2][r] = 0.f;

  f16* Pw = Ps + wv * (32 * 72);

  for (int kt = 0; kt < nIter; ++kt) {
    int bsel = kt & 1;
    int g = gbase + kt;
    // write prefetched K tile (flat) into LDS buffer bsel
    *(uint4*)(&Ks[bsel][t * 8]) = rka;
    if (t < 64) *(uint4*)(&Ks[bsel][(256 + t) * 8]) = rkb;
    // prefetch NEXT tile: K regs + V frags (one-iteration lead hides L2/HBM latency)
    uint4 bvn[3][2];
    bool more = (kt + 1 < nIter);
    if (more) {
      const f16* kn = khb + (size_t)(kt + 1) * 2560;
      rka = *(const uint4*)(kn + t * 8);
      if (t < 64) rkb = *(const uint4*)(kn + (256 + t) * 8);
      load_v_frags(vt_h, bh, (g + 1) << 6, col, quad, bvn);
    }
    __syncthreads();

    // ---- S^T: acc[mt][nt] ----
    f32x4 acc[4][2];
#pragma unroll
    for (int mt = 0; mt < 4; ++mt) {
      int row = mt * 16 + col;
      half8 ak0 = *(half8*)(&Ks[bsel][row * 40 + quad * 8]);
      const f16* pa1 = (quad == 0) ? &Ks[bsel][row * 40 + 32] : Zro;
      half8 ak1 = *(half8*)pa1;
#pragma unroll
      for (int nt = 0; nt < 2; ++nt) {
        f32x4 a; a[0] = 0.f; a[1] = 0.f; a[2] = 0.f; a[3] = 0.f;
        a = MFMA16(ak0, bq[nt][0], a);
        a = MFMA16(ak1, bq[nt][1], a);
        acc[mt][nt] = a;
      }
    }
    bool lastt = (g == 64);
    // ---- P = exp2(s*c1l - mfix) (bound guarantees arg <= 14; no clamp needed) ----
#pragma unroll
    for (int mt = 0; mt < 4; ++mt)
#pragma unroll
      for (int nt = 0; nt < 2; ++nt) {
        float p[4];
#pragma unroll
        for (int r = 0; r < 4; ++r) {
          p[r] = __builtin_amdgcn_exp2f(fmaf(acc[mt][nt][r], c1l, -mfl[nt]));
          if (lastt && (mt * 16 + quad * 4 + r) != 0) p[r] = 0.f;  // keys > 4096
        }
        half2v lo = __builtin_bit_cast(half2v, __builtin_amdgcn_cvt_pkrtz(p[0], p[1]));
        half2v hi = __builtin_bit_cast(half2v, __builtin_amdgcn_cvt_pkrtz(p[2], p[3]));
        half4v pk; pk.lo = lo; pk.hi = hi;
        *(half4v*)(Pw + (nt * 16 + col) * 72 + mt * 16 + quad * 4) = pk;
      }
    // ---- o += P·V^T (V frags prefetched last iteration) ----
#pragma unroll
    for (int kk2 = 0; kk2 < 2; ++kk2) {
      half8 ap0 = *(half8*)(Pw + col * 72 + kk2 * 32 + quad * 8);
      half8 ap1 = *(half8*)(Pw + (16 + col) * 72 + kk2 * 32 + quad * 8);
#pragma unroll
      for (int nv = 0; nv < 3; ++nv) {
        half8 bv = __builtin_bit_cast(half8, bvc[nv][kk2]);
        o_[0][nv] = MFMA16(ap0, bv, o_[0][nv]);
        o_[1][nv] = MFMA16(ap1, bv, o_[1][nv]);
      }
    }
    // rotate V double-buffer
    if (more) {
#pragma unroll
      for (int nv = 0; nv < 3; ++nv)
#pragma unroll
        for (int kk2 = 0; kk2 < 2; ++kk2) bvc[nv][kk2] = bvn[nv][kk2];
    }
  }

  // ---- epilogue: store partial o (cols 0..39) + partial l (col 40) ----
  float* pb = pacc + (size_t)(ks * 16 + bh) * 4096 * 48;
#pragma unroll
  for (int mtq = 0; mtq < 2; ++mtq)
#pragma unroll
    for (int nv = 0; nv < 3; ++nv)
#pragma unroll
      for (int r = 0; r < 4; ++r) {
        int q = qbase + wv * 32 + mtq * 16 + quad * 4 + r;
        pb[(size_t)q * 48 + nv * 16 + col] = o_[mtq][nv][r];
      }
}

// ---------------- K4: combine K-split partials + LayerNorm + residual + upsample --------
__global__ __launch_bounds__(256) void k_ln_out(
    const float* __restrict__ pacc, const float* __restrict__ lnw,
    const float* __restrict__ lnb, float* __restrict__ out) {
  __shared__ float g[64 * 161];
  __shared__ float linv[64 * 4];
  int y = blockIdx.x, b = blockIdx.y, t = threadIdx.x;
  const size_t P1 = (size_t)16 * 4096 * 48;
  {
    int row = t >> 2, h = t & 3;
    size_t i0 = ((size_t)(b * 4 + h) * 4096 + y * 64 + row) * 48 + 40;
    linv[row * 4 + h] = 1.f / (pacc[i0] + pacc[P1 + i0]);
  }
  __syncthreads();
  for (int i = t; i < 10240; i += 256) {
    int row = i / 160, c = i - row * 160;
    int h = c / 40, d = c - h * 40;
    size_t idx = ((size_t)(b * 4 + h) * 4096 + y * 64 + row) * 48 + d;
    g[row * 161 + c] = (pacc[idx] + pacc[P1 + idx]) * linv[row * 4 + h];
  }
  __syncthreads();
  int row = t >> 2, part = t & 3;
  float* gr = g + row * 161 + part * 40;
  float s1 = 0.f, s2 = 0.f;
#pragma unroll
  for (int j = 0; j < 40; ++j) { float v = gr[j]; s1 += v; s2 += v * v; }
  s1 += __shfl_xor(s1, 1); s1 += __shfl_xor(s1, 2);
  s2 += __shfl_xor(s2, 1); s2 += __shfl_xor(s2, 2);
  float mu = s1 * (1.f / 160.f);
  float var = s2 * (1.f / 160.f) - mu * mu;
  float inv = rsqrtf(var + 1e-5f);
  const float* lw = lnw + part * 40;
  const float* lb = lnb + part * 40;
#pragma unroll
  for (int j = 0; j < 40; ++j) {
    float v = gr[j];
    gr[j] = (v - mu) * inv * lw[j] + lb[j] + v;
  }
  __syncthreads();
  int Yo = t >> 7, X = t & 127, rl = X >> 1;
  float* ob = out + ((b * 160) * 128 + (2 * y + Yo)) * 128 + X;
#pragma unroll 4
  for (int c = 0; c < 160; ++c) ob[c * 16384] = g[rl * 161 + c];
}

extern "C" void kernel_launch(void* const* d_in, const int* in_sizes, int n_in,
                              void* d_out, int out_size, void* d_ws, size_t ws_size,
                              hipStream_t stream) {
  const float* x   = (const float*)d_in[0];
  const float* w1  = (const float*)d_in[1];
  const float* b1  = (const float*)d_in[2];
  const float* w2  = (const float*)d_in[3];
  const float* b2  = (const float*)d_in[4];
  const float* pe  = (const float*)d_in[5];
  const float* wq  = (const float*)d_in[6];
  const float* wk  = (const float*)d_in[7];
  const float* wvp = (const float*)d_in[8];
  const float* lnw = (const float*)d_in[9];
  const float* lnb = (const float*)d_in[10];
  float* out = (float*)d_out;

  char* p = (char*)d_ws;
  f16* f_h   = (f16*)p;   p += 4 * 4097 * 160 * 2;        // 5,244,160
  float* w2t = (float*)p; p += 64 * 160 * 4;              // 40,960
  f16* q_h   = (f16*)p;   p += (size_t)16 * 4097 * 40 * 2;  // 5,244,160
  f16* k_h   = (f16*)p;   p += (size_t)16 * 4160 * 40 * 2;  // 5,324,800
  f16* vt_h  = (f16*)p;   p += (size_t)16 * 40 * 4160 * 2;  // 5,324,800
  float* pacc = (float*)p; p += (size_t)2 * 16 * 4096 * 48 * 4;  // 25,165,824
  int* maxk2 = (int*)p;   p += 16 * 4;
  // total ~46.3 MB

  k_prep<<<43, 256, 0, stream>>>(w2, pe, w2t, f_h, maxk2);
  k_conv<<<dim3(64, 4), 256, 0, stream>>>(x, w1, b1, w2t, b2, pe, f_h);
  k_qkv<<<dim3(65, 4), 256, 0, stream>>>(f_h, wq, wk, wvp, q_h, k_h, vt_h);
  k_norm1<<<128, 256, 0, stream>>>(k_h, maxk2);
  k_attn<<<dim3(32, 16, 2), 256, 0, stream>>>(q_h, k_h, vt_h, maxk2, pacc);
  k_ln_out<<<dim3(64, 4), 256, 0, stream>>>(pacc, lnw, lnb, out);
}

// Round 8
// 261.370 us; speedup vs baseline: 1.6701x; 1.6701x over previous
//
#include <hip/hip_runtime.h>

typedef _Float16 f16;
typedef _Float16 half2v __attribute__((ext_vector_type(2)));
typedef _Float16 half4v __attribute__((ext_vector_type(4)));
typedef _Float16 half8 __attribute__((ext_vector_type(8)));
typedef float f32x4 __attribute__((ext_vector_type(4)));

#define MFMA16(a, b, c) __builtin_amdgcn_mfma_f32_16x16x32_f16((a), (b), (c), 0, 0, 0)

// Sizes: B=4, CI=64, H=W=128 ; conv out 64x64 ; C=160 ; S=4097 ; SQ=4096 ; NH=4 ; HD=40
// q layout: [bh(16)][s(4097)][40] f16 packed
// k layout: [bh(16)][s(4160)][40] f16 packed (rows 4097.. uninit, masked on last tile)
// vt layout: [bh(16)][d(40)][4160] f16
// pacc: [ks(2)][bh(16)][q(4096)][48] f32 partial o; col 40 = partial l (ones-column trick)
// Softmax: P = exp2(s*scale*log2e - mfix), mfix = |q|*maxK*scale*log2e - 14 (Cauchy-Schwarz
// bound; Delta=14 keeps f16 P out of subnormals). Fixed shift => K-split partials add linearly.
// R7 lesson: V reg-dbuf spilled to scratch (WRITE_SIZE 690MB). R8: V prefetched one iter
// ahead through LDS dbuf (8 transient staging regs, like K) -- lead time without reg cost.

// ---------------- K0: prep (w2 transpose, f pad row, maxk2 init) ----------------
__global__ __launch_bounds__(256) void k_prep(
    const float* __restrict__ w2, const float* __restrict__ pe,
    float* __restrict__ w2t, f16* __restrict__ f_h, int* __restrict__ maxk2) {
  int i = blockIdx.x * 256 + threadIdx.x;
  if (i < 10240) {                       // w2t[co][c2] = w2[c2][co]
    int co = i / 160, c2 = i - co * 160;
    w2t[co * 160 + c2] = w2[c2 * 64 + co];
  } else if (i < 10880) {                // f[b][4096][c] = pe[4096]
    int j = i - 10240;
    int bb = j / 160, c = j - bb * 160;
    f_h[(bb * 4097 + 4096) * 160 + c] = (f16)pe[4096];
  } else if (i < 10896) {                // maxk2 init (0 as int == 0.0f; sums are > 0)
    maxk2[i - 10880] = 0;
  }
}

// ---------------- K1: conv1(2x2 s2) + b1 + conv2(1x1) + b2 + leaky + pe -> f fp16 -------
__global__ __launch_bounds__(256) void k_conv(
    const float* __restrict__ x, const float* __restrict__ w1, const float* __restrict__ b1,
    const float* __restrict__ w2t, const float* __restrict__ b2, const float* __restrict__ pe,
    f16* __restrict__ f_h) {
  __shared__ float xin[32 * 4 * 64];
  __shared__ float c1[64 * 64];
  int y = blockIdx.x, b = blockIdx.y;
  int t = threadIdx.x, lane = t & 63, wv = t >> 6;
  const float* xb = x + (b * 64) * 16384 + (2 * y) * 128;

  int cob = __builtin_amdgcn_readfirstlane(wv * 16);
  float acc[16];
#pragma unroll
  for (int j = 0; j < 16; ++j) acc[j] = b1[cob + j];

  for (int half = 0; half < 2; ++half) {
    __syncthreads();
    for (int k = 0; k < 32; ++k) {
      int i = t + (k << 8);
      int cil = i >> 8, rem = i & 255, r = rem >> 7, col = rem & 127;
      xin[(cil * 4 + r * 2 + (col & 1)) * 64 + (col >> 1)] =
          xb[(half * 32 + cil) * 16384 + r * 128 + col];
    }
    __syncthreads();
    for (int cil = 0; cil < 32; ++cil) {
      int ci = half * 32 + cil;
      float x00 = xin[(cil * 4 + 0) * 64 + lane];
      float x01 = xin[(cil * 4 + 1) * 64 + lane];
      float x10 = xin[(cil * 4 + 2) * 64 + lane];
      float x11 = xin[(cil * 4 + 3) * 64 + lane];
      const float* wr = w1 + (cob * 64 + ci) * 4;
#pragma unroll
      for (int j = 0; j < 16; ++j) {
        acc[j] += wr[j * 256 + 0] * x00 + wr[j * 256 + 1] * x01 +
                  wr[j * 256 + 2] * x10 + wr[j * 256 + 3] * x11;
      }
    }
  }
#pragma unroll
  for (int j = 0; j < 16; ++j) c1[(cob + j) * 64 + lane] = acc[j];
  __syncthreads();

  int c2b = __builtin_amdgcn_readfirstlane(wv * 40);
  float a2[40];
#pragma unroll
  for (int j = 0; j < 40; ++j) a2[j] = b2[c2b + j];
  for (int co = 0; co < 64; ++co) {
    float xv = c1[co * 64 + lane];
    const float* wr = w2t + co * 160 + c2b;
#pragma unroll
    for (int j = 0; j < 40; ++j) a2[j] += xv * wr[j];
  }
  int s = y * 64 + lane;
  float pes = pe[s];
  f16* dst = f_h + (b * 4097 + s) * 160 + c2b;
#pragma unroll
  for (int j = 0; j < 40; ++j) {
    float v = a2[j];
    v = (v >= 0.f) ? v : 0.01f * v;
    v += pes;
    dst[j] = (f16)v;
  }
}

// ---------------- K2: QKV gemms via MFMA (f32 weights converted during staging) ---------
__global__ __launch_bounds__(256) void k_qkv(
    const f16* __restrict__ f_h,
    const float* __restrict__ wq, const float* __restrict__ wk, const float* __restrict__ wv,
    f16* __restrict__ q_h, f16* __restrict__ k_h, f16* __restrict__ vt_h) {
  __shared__ __attribute__((aligned(16))) f16 fT[64 * 168];
  __shared__ __attribute__((aligned(16))) f16 wT[80 * 168];
  int sb = blockIdx.x, b = blockIdx.y;
  int s0 = sb * 64;
  int t = threadIdx.x, lane = t & 63, wv2 = t >> 6, quad = lane >> 4, col = lane & 15;

  for (int c = t; c < 1280; c += 256) {
    int row = c / 20, seg = c - row * 20;
    int srow = s0 + row; if (srow > 4096) srow = 4096;
    *(uint4*)(fT + row * 168 + seg * 8) =
        *(const uint4*)(f_h + (b * 4097 + srow) * 160 + seg * 8);
  }
  __syncthreads();
  half8 af[5];
  int rowA = wv2 * 16 + col;
#pragma unroll
  for (int kk = 0; kk < 5; ++kk)
    af[kk] = *(half8*)(fT + rowA * 168 + kk * 32 + quad * 8);

  for (int kind = 0; kind < 3; ++kind) {
    const float* wsp = (kind == 0) ? wq : (kind == 1 ? wk : wv);
    for (int hf = 0; hf < 2; ++hf) {
      __syncthreads();
      for (int c = t; c < 1600; c += 256) {
        int row = c / 20, seg = c - row * 20;
        const float* src = wsp + (hf * 80 + row) * 160 + seg * 8;
        f32x4 va = *(const f32x4*)src;
        f32x4 vb = *(const f32x4*)(src + 4);
        uint4 u;
        u.x = __builtin_bit_cast(unsigned, __builtin_amdgcn_cvt_pkrtz(va[0], va[1]));
        u.y = __builtin_bit_cast(unsigned, __builtin_amdgcn_cvt_pkrtz(va[2], va[3]));
        u.z = __builtin_bit_cast(unsigned, __builtin_amdgcn_cvt_pkrtz(vb[0], vb[1]));
        u.w = __builtin_bit_cast(unsigned, __builtin_amdgcn_cvt_pkrtz(vb[2], vb[3]));
        *(uint4*)(wT + row * 168 + seg * 8) = u;
      }
      __syncthreads();
#pragma unroll
      for (int n0 = 0; n0 < 5; ++n0) {
        f32x4 acc; acc[0] = 0.f; acc[1] = 0.f; acc[2] = 0.f; acc[3] = 0.f;
        int rowB = n0 * 16 + col;
#pragma unroll
        for (int kk = 0; kk < 5; ++kk) {
          half8 bf = *(half8*)(wT + rowB * 168 + kk * 32 + quad * 8);
          acc = MFMA16(af[kk], bf, acc);
        }
        int o = (hf * 5 + n0) * 16 + col;
        int hh = o / 40, d = o - hh * 40;
        int bh = b * 4 + hh;
#pragma unroll
        for (int r = 0; r < 4; ++r) {
          int s = s0 + wv2 * 16 + quad * 4 + r;
          if (s <= 4096) {
            f16 v = (f16)acc[r];
            if (kind == 0)      q_h[((size_t)bh * 4097 + s) * 40 + d] = v;
            else if (kind == 1) k_h[((size_t)bh * 4160 + s) * 40 + d] = v;
            else                vt_h[((size_t)bh * 40 + d) * 4160 + s] = v;
          }
        }
      }
    }
  }
}

// ---------------- K2b: per-head max ||k||^2 (packed stride 40) ----------------
__global__ __launch_bounds__(256) void k_norm1(const f16* __restrict__ k_h,
                                               int* __restrict__ maxk2) {
  int bh = blockIdx.x >> 3, chunk = blockIdx.x & 7;
  int t = threadIdx.x;
  int lo = chunk * 513, hi = lo + 513; if (hi > 4097) hi = 4097;
  float mx = 0.f;
  for (int i = lo + t; i < hi; i += 256) {
    const f16* kr = k_h + ((size_t)bh * 4160 + i) * 40;
    float s = 0.f;
#pragma unroll
    for (int c = 0; c < 5; ++c) {
      half8 v = *(const half8*)(kr + c * 8);
#pragma unroll
      for (int j = 0; j < 8; ++j) { float f = (float)v[j]; s += f * f; }
    }
    mx = fmaxf(mx, s);
  }
#pragma unroll
  for (int d = 1; d < 64; d <<= 1) mx = fmaxf(mx, __shfl_xor(mx, d));
  __shared__ float red[4];
  if ((t & 63) == 0) red[t >> 6] = mx;
  __syncthreads();
  if (t == 0) {
    float m = fmaxf(fmaxf(red[0], red[1]), fmaxf(red[2], red[3]));
    atomicMax(maxk2 + bh, __float_as_int(m));
  }
}

// ---------------- K3: flash attention, K-split x2, packed d40, K+V LDS dbuf -------------
// grid (32 qt, 16 bh, 2 ks). 4 waves x 32 q = 128 q/block. One barrier/iter.
// Both K and V tiles prefetched one full iteration ahead: global->regs at top of iter kt
// for tile kt+1, regs->LDS at top of iter kt+1. Staging cost: 16 transient VGPRs.
// LDS: Ks 10240 + Vs 11520 + Ps 18432 + consts 32 = 40224 B -> 4 blocks/CU.
__global__ __launch_bounds__(256, 4) void k_attn(
    const f16* __restrict__ q_h, const f16* __restrict__ k_h,
    const f16* __restrict__ vt_h, const int* __restrict__ maxk2,
    float* __restrict__ pacc) {
  __shared__ __attribute__((aligned(16))) f16 Ks[2][64 * 40];  // packed flat K tile, dbuf
  __shared__ __attribute__((aligned(16))) f16 Vs[2][40 * 72];  // Vt tile [d][key], dbuf
  __shared__ __attribute__((aligned(16))) f16 Ps[4 * 32 * 72]; // per-wave P; Q stage at init
  __shared__ __attribute__((aligned(16))) f16 Ones[8];         // B-rows d>=40: l-col / pad
  __shared__ __attribute__((aligned(16))) f16 Zro[8];

  int qt = blockIdx.x, bh = blockIdx.y, ks = blockIdx.z;
  int qbase = qt * 128;
  int t = threadIdx.x, lane = t & 63, wv = t >> 6, quad = lane >> 4, col = lane & 15;
  const float c1l = 0.15811388300841898f * 1.4426950408889634f;  // scale*log2e
  int gbase = ks * 33;
  int nIter = 33 - ks;  // 33 / 32 tiles

  // ---- stage Q packed [128][40] into Ps; const blocks ----
  const f16* qb = q_h + ((size_t)bh * 4097 + qbase) * 40;
  for (int c = t; c < 640; c += 256)
    *(uint4*)(Ps + c * 8) = *(const uint4*)(qb + c * 8);
  if (t < 8) { Zro[t] = (f16)0; Ones[t] = (f16)1; }

  // ---- tile 0 prefetch into regs (K flat 320x16B; V 40 rows x 4x16B) ----
  const f16* khb = k_h + ((size_t)bh * 4160 + gbase * 64) * 40;
  const f16* vtb = vt_h + (size_t)bh * 40 * 4160;
  int vrow = t >> 3, vseg = t & 7;
  uint4 rka = *(const uint4*)(khb + t * 8);
  uint4 rkb = {0, 0, 0, 0}, rvb = {0, 0, 0, 0};
  if (t < 64) rkb = *(const uint4*)(khb + (256 + t) * 8);
  uint4 rva = *(const uint4*)(vtb + vrow * 4160 + gbase * 64 + vseg * 8);
  if (t < 64) rvb = *(const uint4*)(vtb + (32 + vrow) * 4160 + gbase * 64 + vseg * 8);
  __syncthreads();

  // ---- Q fragments + per-row mfix (fused k_norm2) ----
  half8 bq[2][2];
  float mfl[2];
  float mk = __int_as_float(maxk2[bh]);
#pragma unroll
  for (int nt = 0; nt < 2; ++nt) {
    int row = wv * 32 + nt * 16 + col;
    bq[nt][0] = *(half8*)(Ps + row * 40 + quad * 8);
    const f16* p1 = (quad == 0) ? (Ps + row * 40 + 32) : Zro;
    bq[nt][1] = *(half8*)p1;
    float s = 0.f;
#pragma unroll
    for (int j = 0; j < 8; ++j) {
      float a0 = (float)bq[nt][0][j], a1 = (float)bq[nt][1][j];
      s += a0 * a0 + a1 * a1;
    }
    s += __shfl_xor(s, 16);
    s += __shfl_xor(s, 32);
    mfl[nt] = sqrtf(s * mk) * c1l - 14.0f;  // Delta=14 anti-subnormal boost
  }

  f32x4 o_[2][3];
#pragma unroll
  for (int a = 0; a < 2; ++a)
#pragma unroll
    for (int b2 = 0; b2 < 3; ++b2)
#pragma unroll
      for (int r = 0; r < 4; ++r) o_[a][b2][r] = 0.f;

  f16* Pw = Ps + wv * (32 * 72);

  for (int kt = 0; kt < nIter; ++kt) {
    int bsel = kt & 1;
    int g = gbase + kt;
    // regs -> LDS for tile kt (loaded one iteration ago)
    *(uint4*)(&Ks[bsel][t * 8]) = rka;
    if (t < 64) *(uint4*)(&Ks[bsel][(256 + t) * 8]) = rkb;
    *(uint4*)(&Vs[bsel][vrow * 72 + vseg * 8]) = rva;
    if (t < 64) *(uint4*)(&Vs[bsel][(32 + vrow) * 72 + vseg * 8]) = rvb;
    // global -> regs for tile kt+1 (full-iteration latency lead)
    if (kt + 1 < nIter) {
      const f16* kn = khb + (size_t)(kt + 1) * 2560;
      int k0n = (g + 1) << 6;
      rka = *(const uint4*)(kn + t * 8);
      if (t < 64) rkb = *(const uint4*)(kn + (256 + t) * 8);
      rva = *(const uint4*)(vtb + vrow * 4160 + k0n + vseg * 8);
      if (t < 64) rvb = *(const uint4*)(vtb + (32 + vrow) * 4160 + k0n + vseg * 8);
    }
    __syncthreads();

    // ---- S^T: acc[mt][nt] ----
    f32x4 acc[4][2];
#pragma unroll
    for (int mt = 0; mt < 4; ++mt) {
      int row = mt * 16 + col;
      half8 ak0 = *(half8*)(&Ks[bsel][row * 40 + quad * 8]);
      const f16* pa1 = (quad == 0) ? &Ks[bsel][row * 40 + 32] : Zro;
      half8 ak1 = *(half8*)pa1;
#pragma unroll
      for (int nt = 0; nt < 2; ++nt) {
        f32x4 a; a[0] = 0.f; a[1] = 0.f; a[2] = 0.f; a[3] = 0.f;
        a = MFMA16(ak0, bq[nt][0], a);
        a = MFMA16(ak1, bq[nt][1], a);
        acc[mt][nt] = a;
      }
    }
    bool lastt = (g == 64);
    // ---- P = exp2(s*c1l - mfix) (bound guarantees arg <= 14) ----
#pragma unroll
    for (int mt = 0; mt < 4; ++mt)
#pragma unroll
      for (int nt = 0; nt < 2; ++nt) {
        float p[4];
#pragma unroll
        for (int r = 0; r < 4; ++r) {
          p[r] = __builtin_amdgcn_exp2f(fmaf(acc[mt][nt][r], c1l, -mfl[nt]));
          if (lastt && (mt * 16 + quad * 4 + r) != 0) p[r] = 0.f;  // keys > 4096
        }
        half2v lo = __builtin_bit_cast(half2v, __builtin_amdgcn_cvt_pkrtz(p[0], p[1]));
        half2v hi = __builtin_bit_cast(half2v, __builtin_amdgcn_cvt_pkrtz(p[2], p[3]));
        half4v pk; pk.lo = lo; pk.hi = hi;
        *(half4v*)(Pw + (nt * 16 + col) * 72 + mt * 16 + quad * 4) = pk;
      }
    // ---- o += P·V^T (V from LDS; d>=40 rows from const blocks: d==40 -> l column) ----
#pragma unroll
    for (int kk2 = 0; kk2 < 2; ++kk2) {
      half8 ap0 = *(half8*)(Pw + col * 72 + kk2 * 32 + quad * 8);
      half8 ap1 = *(half8*)(Pw + (16 + col) * 72 + kk2 * 32 + quad * 8);
#pragma unroll
      for (int nv = 0; nv < 3; ++nv) {
        int d = nv * 16 + col;
        const f16* vp = (d < 40) ? &Vs[bsel][d * 72 + kk2 * 32 + quad * 8]
                                 : ((d == 40) ? Ones : Zro);
        half8 bv = *(half8*)vp;
        o_[0][nv] = MFMA16(ap0, bv, o_[0][nv]);
        o_[1][nv] = MFMA16(ap1, bv, o_[1][nv]);
      }
    }
  }

  // ---- epilogue: store partial o (cols 0..39) + partial l (col 40) ----
  float* pb = pacc + (size_t)(ks * 16 + bh) * 4096 * 48;
#pragma unroll
  for (int mtq = 0; mtq < 2; ++mtq)
#pragma unroll
    for (int nv = 0; nv < 3; ++nv)
#pragma unroll
      for (int r = 0; r < 4; ++r) {
        int q = qbase + wv * 32 + mtq * 16 + quad * 4 + r;
        pb[(size_t)q * 48 + nv * 16 + col] = o_[mtq][nv][r];
      }
}

// ---------------- K4: combine K-split partials + LayerNorm + residual + upsample --------
__global__ __launch_bounds__(256) void k_ln_out(
    const float* __restrict__ pacc, const float* __restrict__ lnw,
    const float* __restrict__ lnb, float* __restrict__ out) {
  __shared__ float g[64 * 161];
  __shared__ float linv[64 * 4];
  int y = blockIdx.x, b = blockIdx.y, t = threadIdx.x;
  const size_t P1 = (size_t)16 * 4096 * 48;
  {
    int row = t >> 2, h = t & 3;
    size_t i0 = ((size_t)(b * 4 + h) * 4096 + y * 64 + row) * 48 + 40;
    linv[row * 4 + h] = 1.f / (pacc[i0] + pacc[P1 + i0]);
  }
  __syncthreads();
  for (int i = t; i < 10240; i += 256) {
    int row = i / 160, c = i - row * 160;
    int h = c / 40, d = c - h * 40;
    size_t idx = ((size_t)(b * 4 + h) * 4096 + y * 64 + row) * 48 + d;
    g[row * 161 + c] = (pacc[idx] + pacc[P1 + idx]) * linv[row * 4 + h];
  }
  __syncthreads();
  int row = t >> 2, part = t & 3;
  float* gr = g + row * 161 + part * 40;
  float s1 = 0.f, s2 = 0.f;
#pragma unroll
  for (int j = 0; j < 40; ++j) { float v = gr[j]; s1 += v; s2 += v * v; }
  s1 += __shfl_xor(s1, 1); s1 += __shfl_xor(s1, 2);
  s2 += __shfl_xor(s2, 1); s2 += __shfl_xor(s2, 2);
  float mu = s1 * (1.f / 160.f);
  float var = s2 * (1.f / 160.f) - mu * mu;
  float inv = rsqrtf(var + 1e-5f);
  const float* lw = lnw + part * 40;
  const float* lb = lnb + part * 40;
#pragma unroll
  for (int j = 0; j < 40; ++j) {
    float v = gr[j];
    gr[j] = (v - mu) * inv * lw[j] + lb[j] + v;
  }
  __syncthreads();
  int Yo = t >> 7, X = t & 127, rl = X >> 1;
  float* ob = out + ((b * 160) * 128 + (2 * y + Yo)) * 128 + X;
#pragma unroll 4
  for (int c = 0; c < 160; ++c) ob[c * 16384] = g[rl * 161 + c];
}

extern "C" void kernel_launch(void* const* d_in, const int* in_sizes, int n_in,
                              void* d_out, int out_size, void* d_ws, size_t ws_size,
                              hipStream_t stream) {
  const float* x   = (const float*)d_in[0];
  const float* w1  = (const float*)d_in[1];
  const float* b1  = (const float*)d_in[2];
  const float* w2  = (const float*)d_in[3];
  const float* b2  = (const float*)d_in[4];
  const float* pe  = (const float*)d_in[5];
  const float* wq  = (const float*)d_in[6];
  const float* wk  = (const float*)d_in[7];
  const float* wvp = (const float*)d_in[8];
  const float* lnw = (const float*)d_in[9];
  const float* lnb = (const float*)d_in[10];
  float* out = (float*)d_out;

  char* p = (char*)d_ws;
  f16* f_h   = (f16*)p;   p += 4 * 4097 * 160 * 2;        // 5,244,160
  float* w2t = (float*)p; p += 64 * 160 * 4;              // 40,960
  f16* q_h   = (f16*)p;   p += (size_t)16 * 4097 * 40 * 2;  // 5,244,160
  f16* k_h   = (f16*)p;   p += (size_t)16 * 4160 * 40 * 2;  // 5,324,800
  f16* vt_h  = (f16*)p;   p += (size_t)16 * 40 * 4160 * 2;  // 5,324,800
  float* pacc = (float*)p; p += (size_t)2 * 16 * 4096 * 48 * 4;  // 25,165,824
  int* maxk2 = (int*)p;   p += 16 * 4;
  // total ~46.3 MB

  k_prep<<<43, 256, 0, stream>>>(w2, pe, w2t, f_h, maxk2);
  k_conv<<<dim3(64, 4), 256, 0, stream>>>(x, w1, b1, w2t, b2, pe, f_h);
  k_qkv<<<dim3(65, 4), 256, 0, stream>>>(f_h, wq, wk, wvp, q_h, k_h, vt_h);
  k_norm1<<<128, 256, 0, stream>>>(k_h, maxk2);
  k_attn<<<dim3(32, 16, 2), 256, 0, stream>>>(q_h, k_h, vt_h, maxk2, pacc);
  k_ln_out<<<dim3(64, 4), 256, 0, stream>>>(pacc, lnw, lnb, out);
}

// Round 9
// 258.658 us; speedup vs baseline: 1.6877x; 1.0105x over previous
//
#include <hip/hip_runtime.h>

typedef _Float16 f16;
typedef _Float16 half2v __attribute__((ext_vector_type(2)));
typedef _Float16 half4v __attribute__((ext_vector_type(4)));
typedef _Float16 half8 __attribute__((ext_vector_type(8)));
typedef float f32x4 __attribute__((ext_vector_type(4)));

#define MFMA16(a, b, c) __builtin_amdgcn_mfma_f32_16x16x32_f16((a), (b), (c), 0, 0, 0)

// Sizes: B=4, CI=64, H=W=128 ; conv out 64x64 ; C=160 ; S=4097 ; SQ=4096 ; NH=4 ; HD=40
// q layout: [bh(16)][s(4097)][40] f16 packed
// k layout: [bh(16)][s(4160)][40] f16 packed (rows 4097.. poison, masked on last tile)
// vt layout: [bh(16)][d(40)][4160] f16
// kmaxp: [bh(16)][sb(65)] f32 per-block partial max ||k||^2 (no init needed; all written)
// pacc: [ks(2)][bh(16)][q(4096)][48] f32 partial o; col 40 = partial l (ones-column trick)
// Softmax: P = exp2(s*scale*log2e - mfix), mfix = |q|*maxK*scale*log2e - 14 (Cauchy-Schwarz
// bound; Delta=14 keeps f16 P out of subnormals). Fixed shift => K-split partials add linearly.
// R9: dispatch-count attack -- prep+conv+qkv+norm1 fused into ONE kernel (conv tile == qkv
// input tile for the same block); 6 dispatches -> 3.

// ---------------- K1: conv1+b1+conv2+b2+leaky+pe (in LDS) -> QKV MFMA -> k-norm partials --
__global__ __launch_bounds__(256) void k_convqkv(
    const float* __restrict__ x, const float* __restrict__ w1, const float* __restrict__ b1,
    const float* __restrict__ w2, const float* __restrict__ b2, const float* __restrict__ pe,
    const float* __restrict__ wq, const float* __restrict__ wk, const float* __restrict__ wv,
    f16* __restrict__ q_h, f16* __restrict__ k_h, f16* __restrict__ vt_h,
    float* __restrict__ kmaxp) {
  // LDS union: fT 21504 | [conv: xin 32768 + c1 16384] / [qkv: wT 26880 + red 64]
  __shared__ __attribute__((aligned(16))) char smem[70656];
  f16* fT    = (f16*)smem;                        // 64 x 168 f16
  float* xin = (float*)(smem + 21504);            // 32 x 4 x 64 f32
  float* c1s = (float*)(smem + 54272);            // 64 x 64 f32
  f16* wT    = (f16*)(smem + 21504);              // 80 x 168 f16 (qkv phase, overlays xin)
  float* red = (float*)(smem + 48384);            // 16 f32 (after wT, inside old xin)

  int y = blockIdx.x, b = blockIdx.y;
  int t = threadIdx.x, lane = t & 63, wv4 = t >> 6, quad = lane >> 4, col = lane & 15;
  int s0 = y * 64;

  if (y < 64) {
    // ======== conv phase ========
    const float* xb = x + (b * 64) * 16384 + (2 * y) * 128;
    int cob = __builtin_amdgcn_readfirstlane(wv4 * 16);
    float acc[16];
#pragma unroll
    for (int j = 0; j < 16; ++j) acc[j] = b1[cob + j];
    for (int half = 0; half < 2; ++half) {
      __syncthreads();
      for (int k = 0; k < 32; ++k) {
        int i = t + (k << 8);
        int cil = i >> 8, rem = i & 255, r = rem >> 7, cc = rem & 127;
        xin[(cil * 4 + r * 2 + (cc & 1)) * 64 + (cc >> 1)] =
            xb[(half * 32 + cil) * 16384 + r * 128 + cc];
      }
      __syncthreads();
      for (int cil = 0; cil < 32; ++cil) {
        int ci = half * 32 + cil;
        float x00 = xin[(cil * 4 + 0) * 64 + lane];
        float x01 = xin[(cil * 4 + 1) * 64 + lane];
        float x10 = xin[(cil * 4 + 2) * 64 + lane];
        float x11 = xin[(cil * 4 + 3) * 64 + lane];
        const float* wr = w1 + (cob * 64 + ci) * 4;  // uniform -> s_loads
#pragma unroll
        for (int j = 0; j < 16; ++j) {
          acc[j] += wr[j * 256 + 0] * x00 + wr[j * 256 + 1] * x01 +
                    wr[j * 256 + 2] * x10 + wr[j * 256 + 3] * x11;
        }
      }
    }
#pragma unroll
    for (int j = 0; j < 16; ++j) c1s[(cob + j) * 64 + lane] = acc[j];
    __syncthreads();

    int c2b = __builtin_amdgcn_readfirstlane(wv4 * 40);
    float a2[40];
#pragma unroll
    for (int j = 0; j < 40; ++j) a2[j] = b2[c2b + j];
    for (int co = 0; co < 64; ++co) {
      float xv = c1s[co * 64 + lane];
      // w2[(c2b+j)*64 + co]: wave-uniform strided -> s_loads (w2t transpose eliminated)
#pragma unroll
      for (int j = 0; j < 40; ++j) a2[j] += xv * w2[(c2b + j) * 64 + co];
    }
    float pes = pe[s0 + lane];
#pragma unroll
    for (int j = 0; j < 40; ++j) {
      float v = a2[j];
      v = (v >= 0.f) ? v : 0.01f * v;  // leaky BEFORE pe add
      v += pes;
      fT[lane * 168 + c2b + j] = (f16)v;
    }
  } else {
    // pad-row block: every fT row = pe[4096] (only s==4096 is stored later)
    f16 ph = (f16)pe[4096];
    for (int i = t; i < 10240; i += 256) {
      int row = i / 160, c = i - row * 160;
      fT[row * 168 + c] = ph;
    }
  }
  __syncthreads();

  // ======== QKV phase ========
  half8 af[5];
  int rowA = wv4 * 16 + col;
#pragma unroll
  for (int kk = 0; kk < 5; ++kk)
    af[kk] = *(half8*)(fT + rowA * 168 + kk * 32 + quad * 8);

  float ks0[4], ks1[4];
#pragma unroll
  for (int r = 0; r < 4; ++r) { ks0[r] = 0.f; ks1[r] = 0.f; }

  for (int kind = 0; kind < 3; ++kind) {
    const float* wsp = (kind == 0) ? wq : (kind == 1 ? wk : wv);
    for (int hf = 0; hf < 2; ++hf) {
      __syncthreads();
      for (int c = t; c < 1600; c += 256) {
        int row = c / 20, seg = c - row * 20;
        const float* src = wsp + (hf * 80 + row) * 160 + seg * 8;
        f32x4 va = *(const f32x4*)src;
        f32x4 vb = *(const f32x4*)(src + 4);
        uint4 u;
        u.x = __builtin_bit_cast(unsigned, __builtin_amdgcn_cvt_pkrtz(va[0], va[1]));
        u.y = __builtin_bit_cast(unsigned, __builtin_amdgcn_cvt_pkrtz(va[2], va[3]));
        u.z = __builtin_bit_cast(unsigned, __builtin_amdgcn_cvt_pkrtz(vb[0], vb[1]));
        u.w = __builtin_bit_cast(unsigned, __builtin_amdgcn_cvt_pkrtz(vb[2], vb[3]));
        *(uint4*)(wT + row * 168 + seg * 8) = u;
      }
      __syncthreads();
#pragma unroll
      for (int n0 = 0; n0 < 5; ++n0) {
        f32x4 acc; acc[0] = 0.f; acc[1] = 0.f; acc[2] = 0.f; acc[3] = 0.f;
        int rowB = n0 * 16 + col;
#pragma unroll
        for (int kk = 0; kk < 5; ++kk) {
          half8 bf = *(half8*)(wT + rowB * 168 + kk * 32 + quad * 8);
          acc = MFMA16(af[kk], bf, acc);
        }
        int o = (hf * 5 + n0) * 16 + col;
        int hh = o / 40, d = o - hh * 40;
        int bh = b * 4 + hh;
        if (kind == 1) {  // accumulate ||k||^2 per head-within-hf (kidx), per row r
          bool kidx = (n0 * 16 + col) >= 40;
#pragma unroll
          for (int r = 0; r < 4; ++r) {
            float z = acc[r] * acc[r];
            ks0[r] += kidx ? 0.f : z;
            ks1[r] += kidx ? z : 0.f;
          }
        }
#pragma unroll
        for (int r = 0; r < 4; ++r) {
          int s = s0 + wv4 * 16 + quad * 4 + r;
          if (s <= 4096) {
            f16 v = (f16)acc[r];
            if (kind == 0)      q_h[((size_t)bh * 4097 + s) * 40 + d] = v;
            else if (kind == 1) k_h[((size_t)bh * 4160 + s) * 40 + d] = v;
            else                vt_h[((size_t)bh * 40 + d) * 4160 + s] = v;
          }
        }
      }
      if (kind == 1) {  // flush per-hf partial max (heads hf*2, hf*2+1)
        float m0 = 0.f, m1 = 0.f;
#pragma unroll
        for (int r = 0; r < 4; ++r) {
          float v0 = ks0[r], v1 = ks1[r];
          v0 += __shfl_xor(v0, 1); v0 += __shfl_xor(v0, 2);
          v0 += __shfl_xor(v0, 4); v0 += __shfl_xor(v0, 8);
          v1 += __shfl_xor(v1, 1); v1 += __shfl_xor(v1, 2);
          v1 += __shfl_xor(v1, 4); v1 += __shfl_xor(v1, 8);
          m0 = fmaxf(m0, v0); m1 = fmaxf(m1, v1);
          ks0[r] = 0.f; ks1[r] = 0.f;
        }
        m0 = fmaxf(m0, __shfl_xor(m0, 16)); m0 = fmaxf(m0, __shfl_xor(m0, 32));
        m1 = fmaxf(m1, __shfl_xor(m1, 16)); m1 = fmaxf(m1, __shfl_xor(m1, 32));
        if (lane == 0) { red[wv4 * 4 + hf * 2] = m0; red[wv4 * 4 + hf * 2 + 1] = m1; }
      }
    }
  }
  __syncthreads();
  if (t < 4) {  // t = head index hh
    float m = fmaxf(fmaxf(red[t], red[4 + t]), fmaxf(red[8 + t], red[12 + t]));
    kmaxp[(b * 4 + t) * 65 + y] = m;
  }
}

// ---------------- K2: flash attention, K-split x2, packed d40, K+V LDS dbuf -------------
// grid (32 qt, 16 bh, 2 ks). 4 waves x 32 q = 128 q/block. One barrier/iter.
// K and V tiles prefetched one full iteration ahead (R7 lesson: through LDS, not regs).
__global__ __launch_bounds__(256, 4) void k_attn(
    const f16* __restrict__ q_h, const f16* __restrict__ k_h,
    const f16* __restrict__ vt_h, const float* __restrict__ kmaxp,
    float* __restrict__ pacc) {
  __shared__ __attribute__((aligned(16))) f16 Ks[2][64 * 40];  // packed flat K tile, dbuf
  __shared__ __attribute__((aligned(16))) f16 Vs[2][40 * 72];  // Vt tile [d][key], dbuf
  __shared__ __attribute__((aligned(16))) f16 Ps[4 * 32 * 72]; // per-wave P; Q stage at init
  __shared__ __attribute__((aligned(16))) f16 Ones[8];         // B-rows d>=40: l-col / pad
  __shared__ __attribute__((aligned(16))) f16 Zro[8];
  __shared__ __attribute__((aligned(16))) float red4[4];

  int qt = blockIdx.x, bh = blockIdx.y, ks = blockIdx.z;
  int qbase = qt * 128;
  int t = threadIdx.x, lane = t & 63, wv = t >> 6, quad = lane >> 4, col = lane & 15;
  const float c1l = 0.15811388300841898f * 1.4426950408889634f;  // scale*log2e
  int gbase = ks * 33;
  int nIter = 33 - ks;  // 33 / 32 tiles

  // ---- stage Q packed [128][40] into Ps; const blocks; kmaxp block-reduce ----
  const f16* qb = q_h + ((size_t)bh * 4097 + qbase) * 40;
  for (int c = t; c < 640; c += 256)
    *(uint4*)(Ps + c * 8) = *(const uint4*)(qb + c * 8);
  if (t < 8) { Zro[t] = (f16)0; Ones[t] = (f16)1; }
  {
    float vm = (t < 65) ? kmaxp[bh * 65 + t] : 0.f;
#pragma unroll
    for (int d = 1; d < 64; d <<= 1) vm = fmaxf(vm, __shfl_xor(vm, d));
    if (lane == 0) red4[wv] = vm;
  }

  // ---- tile 0 prefetch into regs (K flat 320x16B; V 40 rows x 4x16B) ----
  const f16* khb = k_h + ((size_t)bh * 4160 + gbase * 64) * 40;
  const f16* vtb = vt_h + (size_t)bh * 40 * 4160;
  int vrow = t >> 3, vseg = t & 7;
  uint4 rka = *(const uint4*)(khb + t * 8);
  uint4 rkb = {0, 0, 0, 0}, rvb = {0, 0, 0, 0};
  if (t < 64) rkb = *(const uint4*)(khb + (256 + t) * 8);
  uint4 rva = *(const uint4*)(vtb + vrow * 4160 + gbase * 64 + vseg * 8);
  if (t < 64) rvb = *(const uint4*)(vtb + (32 + vrow) * 4160 + gbase * 64 + vseg * 8);
  __syncthreads();

  float mk = fmaxf(fmaxf(red4[0], red4[1]), fmaxf(red4[2], red4[3]));

  // ---- Q fragments + per-row mfix ----
  half8 bq[2][2];
  float mfl[2];
#pragma unroll
  for (int nt = 0; nt < 2; ++nt) {
    int row = wv * 32 + nt * 16 + col;
    bq[nt][0] = *(half8*)(Ps + row * 40 + quad * 8);
    const f16* p1 = (quad == 0) ? (Ps + row * 40 + 32) : Zro;
    bq[nt][1] = *(half8*)p1;
    float s = 0.f;
#pragma unroll
    for (int j = 0; j < 8; ++j) {
      float a0 = (float)bq[nt][0][j], a1 = (float)bq[nt][1][j];
      s += a0 * a0 + a1 * a1;
    }
    s += __shfl_xor(s, 16);
    s += __shfl_xor(s, 32);
    mfl[nt] = sqrtf(s * mk) * c1l - 14.0f;  // Delta=14 anti-subnormal boost
  }

  f32x4 o_[2][3];
#pragma unroll
  for (int a = 0; a < 2; ++a)
#pragma unroll
    for (int b2 = 0; b2 < 3; ++b2)
#pragma unroll
      for (int r = 0; r < 4; ++r) o_[a][b2][r] = 0.f;

  f16* Pw = Ps + wv * (32 * 72);

  for (int kt = 0; kt < nIter; ++kt) {
    int bsel = kt & 1;
    int g = gbase + kt;
    // regs -> LDS for tile kt (loaded one iteration ago)
    *(uint4*)(&Ks[bsel][t * 8]) = rka;
    if (t < 64) *(uint4*)(&Ks[bsel][(256 + t) * 8]) = rkb;
    *(uint4*)(&Vs[bsel][vrow * 72 + vseg * 8]) = rva;
    if (t < 64) *(uint4*)(&Vs[bsel][(32 + vrow) * 72 + vseg * 8]) = rvb;
    // global -> regs for tile kt+1 (full-iteration latency lead)
    if (kt + 1 < nIter) {
      const f16* kn = khb + (size_t)(kt + 1) * 2560;
      int k0n = (g + 1) << 6;
      rka = *(const uint4*)(kn + t * 8);
      if (t < 64) rkb = *(const uint4*)(kn + (256 + t) * 8);
      rva = *(const uint4*)(vtb + vrow * 4160 + k0n + vseg * 8);
      if (t < 64) rvb = *(const uint4*)(vtb + (32 + vrow) * 4160 + k0n + vseg * 8);
    }
    __syncthreads();

    // ---- S^T: acc[mt][nt] ----
    f32x4 acc[4][2];
#pragma unroll
    for (int mt = 0; mt < 4; ++mt) {
      int row = mt * 16 + col;
      half8 ak0 = *(half8*)(&Ks[bsel][row * 40 + quad * 8]);
      const f16* pa1 = (quad == 0) ? &Ks[bsel][row * 40 + 32] : Zro;
      half8 ak1 = *(half8*)pa1;
#pragma unroll
      for (int nt = 0; nt < 2; ++nt) {
        f32x4 a; a[0] = 0.f; a[1] = 0.f; a[2] = 0.f; a[3] = 0.f;
        a = MFMA16(ak0, bq[nt][0], a);
        a = MFMA16(ak1, bq[nt][1], a);
        acc[mt][nt] = a;
      }
    }
    bool lastt = (g == 64);
    // ---- P = exp2(s*c1l - mfix) ----
#pragma unroll
    for (int mt = 0; mt < 4; ++mt)
#pragma unroll
      for (int nt = 0; nt < 2; ++nt) {
        float p[4];
#pragma unroll
        for (int r = 0; r < 4; ++r) {
          p[r] = __builtin_amdgcn_exp2f(fmaf(acc[mt][nt][r], c1l, -mfl[nt]));
          if (lastt && (mt * 16 + quad * 4 + r) != 0) p[r] = 0.f;  // keys > 4096
        }
        half2v lo = __builtin_bit_cast(half2v, __builtin_amdgcn_cvt_pkrtz(p[0], p[1]));
        half2v hi = __builtin_bit_cast(half2v, __builtin_amdgcn_cvt_pkrtz(p[2], p[3]));
        half4v pk; pk.lo = lo; pk.hi = hi;
        *(half4v*)(Pw + (nt * 16 + col) * 72 + mt * 16 + quad * 4) = pk;
      }
    // ---- o += P·V^T (V from LDS; d>=40 rows from const blocks: d==40 -> l column) ----
#pragma unroll
    for (int kk2 = 0; kk2 < 2; ++kk2) {
      half8 ap0 = *(half8*)(Pw + col * 72 + kk2 * 32 + quad * 8);
      half8 ap1 = *(half8*)(Pw + (16 + col) * 72 + kk2 * 32 + quad * 8);
#pragma unroll
      for (int nv = 0; nv < 3; ++nv) {
        int d = nv * 16 + col;
        const f16* vp = (d < 40) ? &Vs[bsel][d * 72 + kk2 * 32 + quad * 8]
                                 : ((d == 40) ? Ones : Zro);
        half8 bv = *(half8*)vp;
        o_[0][nv] = MFMA16(ap0, bv, o_[0][nv]);
        o_[1][nv] = MFMA16(ap1, bv, o_[1][nv]);
      }
    }
  }

  // ---- epilogue: store partial o (cols 0..39) + partial l (col 40) ----
  float* pb = pacc + (size_t)(ks * 16 + bh) * 4096 * 48;
#pragma unroll
  for (int mtq = 0; mtq < 2; ++mtq)
#pragma unroll
    for (int nv = 0; nv < 3; ++nv)
#pragma unroll
      for (int r = 0; r < 4; ++r) {
        int q = qbase + wv * 32 + mtq * 16 + quad * 4 + r;
        pb[(size_t)q * 48 + nv * 16 + col] = o_[mtq][nv][r];
      }
}

// ---------------- K3: combine K-split partials + LayerNorm + residual + upsample --------
__global__ __launch_bounds__(256) void k_ln_out(
    const float* __restrict__ pacc, const float* __restrict__ lnw,
    const float* __restrict__ lnb, float* __restrict__ out) {
  __shared__ float g[64 * 161];
  __shared__ float linv[64 * 4];
  int y = blockIdx.x, b = blockIdx.y, t = threadIdx.x;
  const size_t P1 = (size_t)16 * 4096 * 48;
  {
    int row = t >> 2, h = t & 3;
    size_t i0 = ((size_t)(b * 4 + h) * 4096 + y * 64 + row) * 48 + 40;
    linv[row * 4 + h] = 1.f / (pacc[i0] + pacc[P1 + i0]);
  }
  __syncthreads();
  for (int i = t; i < 10240; i += 256) {
    int row = i / 160, c = i - row * 160;
    int h = c / 40, d = c - h * 40;
    size_t idx = ((size_t)(b * 4 + h) * 4096 + y * 64 + row) * 48 + d;
    g[row * 161 + c] = (pacc[idx] + pacc[P1 + idx]) * linv[row * 4 + h];
  }
  __syncthreads();
  int row = t >> 2, part = t & 3;
  float* gr = g + row * 161 + part * 40;
  float s1 = 0.f, s2 = 0.f;
#pragma unroll
  for (int j = 0; j < 40; ++j) { float v = gr[j]; s1 += v; s2 += v * v; }
  s1 += __shfl_xor(s1, 1); s1 += __shfl_xor(s1, 2);
  s2 += __shfl_xor(s2, 1); s2 += __shfl_xor(s2, 2);
  float mu = s1 * (1.f / 160.f);
  float var = s2 * (1.f / 160.f) - mu * mu;
  float inv = rsqrtf(var + 1e-5f);
  const float* lw = lnw + part * 40;
  const float* lb = lnb + part * 40;
#pragma unroll
  for (int j = 0; j < 40; ++j) {
    float v = gr[j];
    gr[j] = (v - mu) * inv * lw[j] + lb[j] + v;
  }
  __syncthreads();
  int Yo = t >> 7, X = t & 127, rl = X >> 1;
  float* ob = out + ((b * 160) * 128 + (2 * y + Yo)) * 128 + X;
#pragma unroll 4
  for (int c = 0; c < 160; ++c) ob[c * 16384] = g[rl * 161 + c];
}

extern "C" void kernel_launch(void* const* d_in, const int* in_sizes, int n_in,
                              void* d_out, int out_size, void* d_ws, size_t ws_size,
                              hipStream_t stream) {
  const float* x   = (const float*)d_in[0];
  const float* w1  = (const float*)d_in[1];
  const float* b1  = (const float*)d_in[2];
  const float* w2  = (const float*)d_in[3];
  const float* b2  = (const float*)d_in[4];
  const float* pe  = (const float*)d_in[5];
  const float* wq  = (const float*)d_in[6];
  const float* wk  = (const float*)d_in[7];
  const float* wvp = (const float*)d_in[8];
  const float* lnw = (const float*)d_in[9];
  const float* lnb = (const float*)d_in[10];
  float* out = (float*)d_out;

  char* p = (char*)d_ws;
  f16* q_h   = (f16*)p;   p += (size_t)16 * 4097 * 40 * 2;       // 5,244,160
  f16* k_h   = (f16*)p;   p += (size_t)16 * 4160 * 40 * 2;       // 5,324,800
  f16* vt_h  = (f16*)p;   p += (size_t)16 * 40 * 4160 * 2;       // 5,324,800
  float* pacc = (float*)p; p += (size_t)2 * 16 * 4096 * 48 * 4;  // 25,165,824
  float* kmaxp = (float*)p; p += 16 * 65 * 4;                    // 4,160
  // total ~41.1 MB

  k_convqkv<<<dim3(65, 4), 256, 0, stream>>>(x, w1, b1, w2, b2, pe, wq, wk, wvp,
                                             q_h, k_h, vt_h, kmaxp);
  k_attn<<<dim3(32, 16, 2), 256, 0, stream>>>(q_h, k_h, vt_h, kmaxp, pacc);
  k_ln_out<<<dim3(64, 4), 256, 0, stream>>>(pacc, lnw, lnb, out);
}

// Round 10
// 218.624 us; speedup vs baseline: 1.9967x; 1.1831x over previous
//
#include <hip/hip_runtime.h>

typedef _Float16 f16;
typedef _Float16 half2v __attribute__((ext_vector_type(2)));
typedef _Float16 half4v __attribute__((ext_vector_type(4)));
typedef _Float16 half8 __attribute__((ext_vector_type(8)));
typedef float f32x4 __attribute__((ext_vector_type(4)));

#define MFMA16(a, b, c) __builtin_amdgcn_mfma_f32_16x16x32_f16((a), (b), (c), 0, 0, 0)

__device__ __forceinline__ unsigned pk2(float a, float b) {
  return __builtin_bit_cast(unsigned, __builtin_amdgcn_cvt_pkrtz(a, b));
}

// Sizes: B=4, CI=64, H=W=128 ; conv out 64x64 ; C=160 ; S=4097 ; SQ=4096 ; NH=4 ; HD=40
// q layout: [bh(16)][s(4097)][40] f16 packed
// k layout: [bh(16)][s(4160)][40] f16 packed (rows 4097.. poison, masked on last tile)
// vt layout: [bh(16)][d(40)][4160] f16
// kmaxp: [bh(16)][65] f32: slots 0..63 per-block partial max ||k||^2, slot 64 = ||k_4096||^2
// pacc: [ks(2)][bh(16)][q(4096)][48] f32 partial o; col 40 = partial l (ones-column trick)
// Softmax: P = exp2(s*scale*log2e - mfix), mfix = |q|*maxK*scale*log2e - 14 (Cauchy-Schwarz
// bound; Delta=14 keeps f16 P out of subnormals). Fixed shift => K-split partials add linearly.
// R10: aux-kernel attack. conv1/conv2 are now MFMA GEMMs (R9's conv was ~50k serial
// VALU+s_load cycles at 1 wave/SIMD; w2 column s_loads alone ~27us). ln_out: 2x blocks +
// vectorized pacc reads. k_attn untouched (LDS-throughput-bound, ~78% of b128 ceiling).

// ---------------- K1: conv1(MFMA) -> conv2(MFMA)+leaky+pe -> QKV(MFMA) + k-norm ---------
__global__ __launch_bounds__(256) void k_convqkv(
    const float* __restrict__ x, const float* __restrict__ w1, const float* __restrict__ b1,
    const float* __restrict__ w2, const float* __restrict__ b2, const float* __restrict__ pe,
    const float* __restrict__ wq, const float* __restrict__ wk, const float* __restrict__ wv,
    f16* __restrict__ q_h, f16* __restrict__ k_h, f16* __restrict__ vt_h,
    float* __restrict__ kmaxp) {
  // LDS map (112192 B, 1 block/CU):
  //   [0,21504)        fT   64x168 f16   (conv2 out = QKV input)
  //   [21504,55360)    xh   64x264 f16 [pos][ciq]   | QKV overlay: wT 80x168 + red(16 f32)
  //   [55360,89152)    w1h  64x264 f16 [co][ciq]    | post-conv1 overlay: c1t 64x72 [pos][co]
  //                                                  | + red160 (pad-row knorm) at +9216
  //   [89152,112192)   w2h 160x72 f16 [c2][co]
  __shared__ __attribute__((aligned(16))) char smem[112192];
  f16* fT   = (f16*)smem;
  f16* xh   = (f16*)(smem + 21504);
  f16* wT   = (f16*)(smem + 21504);
  float* red = (float*)(smem + 48384);
  f16* w1h  = (f16*)(smem + 55360);
  f16* c1t  = (f16*)(smem + 55360);
  float* red160 = (float*)(smem + 64576);
  f16* w2h  = (f16*)(smem + 89152);

  int y = blockIdx.x, b = blockIdx.y;
  int t = threadIdx.x, lane = t & 63, wv4 = t >> 6, quad = lane >> 4, col = lane & 15;
  int s0 = y * 64;

  // ---- phase 1: stage xh (f32->f16, B layout), w1h, w2h ----
  const float* xb = x + (b * 64) * 16384 + (2 * y) * 128;
#pragma unroll
  for (int it = 0; it < 32; ++it) {
    int flat = t + it * 256;  // [0,8192) float2 units
    int pos = flat & 63, r = (flat >> 6) & 1, ci = flat >> 7;
    float2 v = *(const float2*)(xb + ci * 16384 + r * 128 + 2 * pos);
    *(unsigned*)(xh + pos * 264 + ci * 4 + r * 2) = pk2(v.x, v.y);
  }
#pragma unroll
  for (int it = 0; it < 16; ++it) {
    int i4 = t + it * 256;  // [0,4096) f32x4 units of w1 (64x256)
    int co = i4 >> 6, q4 = (i4 & 63) * 4;
    f32x4 v = *(const f32x4*)(w1 + co * 256 + q4);
    uint2 u = {pk2(v[0], v[1]), pk2(v[2], v[3])};
    *(uint2*)(w1h + co * 264 + q4) = u;
  }
#pragma unroll
  for (int it = 0; it < 10; ++it) {
    int i4 = t + it * 256;  // [0,2560) f32x4 units of w2 (160x64)
    int c2 = i4 >> 4, q4 = (i4 & 15) * 4;
    f32x4 v = *(const f32x4*)(w2 + c2 * 160 / 160 * 0 + c2 * 64 + q4);
    uint2 u = {pk2(v[0], v[1]), pk2(v[2], v[3])};
    *(uint2*)(w2h + c2 * 72 + q4) = u;
  }
  __syncthreads();

  // ---- phase 2: conv1 MFMA  c1[co][pos] = w1h[co][.] . xh[pos][.] + b1 ----
  float b1v[4];
#pragma unroll
  for (int r = 0; r < 4; ++r) b1v[r] = b1[wv4 * 16 + quad * 4 + r];
  f32x4 acc1[4];
#pragma unroll
  for (int nt = 0; nt < 4; ++nt)
#pragma unroll
    for (int r = 0; r < 4; ++r) acc1[nt][r] = b1v[r];
#pragma unroll
  for (int kk = 0; kk < 8; ++kk) {
    half8 a = *(half8*)(w1h + (wv4 * 16 + col) * 264 + kk * 32 + quad * 8);
#pragma unroll
    for (int nt = 0; nt < 4; ++nt) {
      half8 bfr = *(half8*)(xh + (nt * 16 + col) * 264 + kk * 32 + quad * 8);
      acc1[nt] = MFMA16(a, bfr, acc1[nt]);
    }
  }
  __syncthreads();  // all w1h reads done before c1t overlay
#pragma unroll
  for (int nt = 0; nt < 4; ++nt) {
    uint2 u = {pk2(acc1[nt][0], acc1[nt][1]), pk2(acc1[nt][2], acc1[nt][3])};
    *(uint2*)(c1t + (nt * 16 + col) * 72 + wv4 * 16 + quad * 4) = u;
  }
  __syncthreads();

  // ---- phase 3: conv2 MFMA  f[pos][c2] = leaky(w2h[c2][.] . c1t[pos][.] + b2) + pe ----
  f32x4 acc2[10];
#pragma unroll
  for (int mt = 0; mt < 10; ++mt)
#pragma unroll
    for (int r = 0; r < 4; ++r) acc2[mt][r] = b2[mt * 16 + quad * 4 + r];
  half8 bb0 = *(half8*)(c1t + (wv4 * 16 + col) * 72 + quad * 8);
  half8 bb1 = *(half8*)(c1t + (wv4 * 16 + col) * 72 + 32 + quad * 8);
#pragma unroll
  for (int mt = 0; mt < 10; ++mt) {
    half8 a0 = *(half8*)(w2h + (mt * 16 + col) * 72 + quad * 8);
    half8 a1 = *(half8*)(w2h + (mt * 16 + col) * 72 + 32 + quad * 8);
    acc2[mt] = MFMA16(a0, bb0, acc2[mt]);
    acc2[mt] = MFMA16(a1, bb1, acc2[mt]);
  }
  float pes = pe[s0 + wv4 * 16 + col];
#pragma unroll
  for (int mt = 0; mt < 10; ++mt) {
    float p[4];
#pragma unroll
    for (int r = 0; r < 4; ++r) {
      float v = acc2[mt][r];
      v = (v >= 0.f) ? v : 0.01f * v;  // leaky BEFORE pe add
      p[r] = v + pes;
    }
    uint2 u = {pk2(p[0], p[1]), pk2(p[2], p[3])};
    *(uint2*)(fT + (wv4 * 16 + col) * 168 + mt * 16 + quad * 4) = u;
  }
  __syncthreads();

  // ---- phase 4: QKV MFMA (weights f32->f16 during staging) + k-norm partials ----
  half8 af[5];
  int rowA = wv4 * 16 + col;
#pragma unroll
  for (int kk = 0; kk < 5; ++kk)
    af[kk] = *(half8*)(fT + rowA * 168 + kk * 32 + quad * 8);

  float ks0[4], ks1[4];
#pragma unroll
  for (int r = 0; r < 4; ++r) { ks0[r] = 0.f; ks1[r] = 0.f; }

  for (int kind = 0; kind < 3; ++kind) {
    const float* wsp = (kind == 0) ? wq : (kind == 1 ? wk : wv);
    for (int hf = 0; hf < 2; ++hf) {
      __syncthreads();
      for (int c = t; c < 1600; c += 256) {
        int row = c / 20, seg = c - row * 20;
        const float* src = wsp + (hf * 80 + row) * 160 + seg * 8;
        f32x4 va = *(const f32x4*)src;
        f32x4 vb = *(const f32x4*)(src + 4);
        uint4 u = {pk2(va[0], va[1]), pk2(va[2], va[3]), pk2(vb[0], vb[1]), pk2(vb[2], vb[3])};
        *(uint4*)(wT + row * 168 + seg * 8) = u;
      }
      __syncthreads();
#pragma unroll
      for (int n0 = 0; n0 < 5; ++n0) {
        f32x4 acc; acc[0] = 0.f; acc[1] = 0.f; acc[2] = 0.f; acc[3] = 0.f;
        int rowB = n0 * 16 + col;
#pragma unroll
        for (int kk = 0; kk < 5; ++kk) {
          half8 bf = *(half8*)(wT + rowB * 168 + kk * 32 + quad * 8);
          acc = MFMA16(af[kk], bf, acc);
        }
        int o = (hf * 5 + n0) * 16 + col;
        int hh = o / 40, d = o - hh * 40;
        int bh = b * 4 + hh;
        if (kind == 1) {
          bool kidx = (n0 * 16 + col) >= 40;
#pragma unroll
          for (int r = 0; r < 4; ++r) {
            float z = acc[r] * acc[r];
            ks0[r] += kidx ? 0.f : z;
            ks1[r] += kidx ? z : 0.f;
          }
        }
#pragma unroll
        for (int r = 0; r < 4; ++r) {
          int s = s0 + wv4 * 16 + quad * 4 + r;  // <= 4095 always (y < 64)
          f16 v = (f16)acc[r];
          if (kind == 0)      q_h[((size_t)bh * 4097 + s) * 40 + d] = v;
          else if (kind == 1) k_h[((size_t)bh * 4160 + s) * 40 + d] = v;
          else                vt_h[((size_t)bh * 40 + d) * 4160 + s] = v;
        }
      }
      if (kind == 1) {
        float m0 = 0.f, m1 = 0.f;
#pragma unroll
        for (int r = 0; r < 4; ++r) {
          float v0 = ks0[r], v1 = ks1[r];
          v0 += __shfl_xor(v0, 1); v0 += __shfl_xor(v0, 2);
          v0 += __shfl_xor(v0, 4); v0 += __shfl_xor(v0, 8);
          v1 += __shfl_xor(v1, 1); v1 += __shfl_xor(v1, 2);
          v1 += __shfl_xor(v1, 4); v1 += __shfl_xor(v1, 8);
          m0 = fmaxf(m0, v0); m1 = fmaxf(m1, v1);
          ks0[r] = 0.f; ks1[r] = 0.f;
        }
        m0 = fmaxf(m0, __shfl_xor(m0, 16)); m0 = fmaxf(m0, __shfl_xor(m0, 32));
        m1 = fmaxf(m1, __shfl_xor(m1, 16)); m1 = fmaxf(m1, __shfl_xor(m1, 32));
        if (lane == 0) { red[wv4 * 4 + hf * 2] = m0; red[wv4 * 4 + hf * 2 + 1] = m1; }
      }
    }
  }
  __syncthreads();
  if (t < 4) {
    float m = fmaxf(fmaxf(red[t], red[4 + t]), fmaxf(red[8 + t], red[12 + t]));
    kmaxp[(b * 4 + t) * 65 + y] = m;
  }

  // ---- pad row s=4096: f[4096][c] = pe[4096] for all c => qkv = pe4096 * rowsum(W) ----
  if (y == 63) {
    float pe4 = pe[4096];
    if (t < 160) {
      int hh = t / 40, d = t - hh * 40, bh = b * 4 + hh;
#pragma unroll
      for (int kind = 0; kind < 3; ++kind) {
        const float* wsp = (kind == 0) ? wq : (kind == 1 ? wk : wv);
        const float* wr = wsp + t * 160;
        float rs = 0.f;
#pragma unroll
        for (int c4 = 0; c4 < 40; ++c4) {
          f32x4 v = *(const f32x4*)(wr + c4 * 4);
          rs += v[0] + v[1] + v[2] + v[3];
        }
        float val = pe4 * rs;
        if (kind == 0)      q_h[((size_t)bh * 4097 + 4096) * 40 + d] = (f16)val;
        else if (kind == 1) { k_h[((size_t)bh * 4160 + 4096) * 40 + d] = (f16)val;
                              red160[t] = val * val; }
        else                vt_h[((size_t)bh * 40 + d) * 4160 + 4096] = (f16)val;
      }
    }
    __syncthreads();
    if (t < 4) {
      float s = 0.f;
#pragma unroll
      for (int j = 0; j < 40; ++j) s += red160[t * 40 + j];
      kmaxp[(b * 4 + t) * 65 + 64] = s;
    }
  }
}

// ---------------- K2: flash attention, K-split x2, packed d40, K+V LDS dbuf -------------
// grid (32 qt, 16 bh, 2 ks). 4 waves x 32 q = 128 q/block. One barrier/iter.
// K and V tiles prefetched one full iteration ahead (R7 lesson: through LDS, not regs).
__global__ __launch_bounds__(256, 4) void k_attn(
    const f16* __restrict__ q_h, const f16* __restrict__ k_h,
    const f16* __restrict__ vt_h, const float* __restrict__ kmaxp,
    float* __restrict__ pacc) {
  __shared__ __attribute__((aligned(16))) f16 Ks[2][64 * 40];
  __shared__ __attribute__((aligned(16))) f16 Vs[2][40 * 72];
  __shared__ __attribute__((aligned(16))) f16 Ps[4 * 32 * 72];
  __shared__ __attribute__((aligned(16))) f16 Ones[8];
  __shared__ __attribute__((aligned(16))) f16 Zro[8];
  __shared__ __attribute__((aligned(16))) float red4[4];

  int qt = blockIdx.x, bh = blockIdx.y, ks = blockIdx.z;
  int qbase = qt * 128;
  int t = threadIdx.x, lane = t & 63, wv = t >> 6, quad = lane >> 4, col = lane & 15;
  const float c1l = 0.15811388300841898f * 1.4426950408889634f;  // scale*log2e
  int gbase = ks * 33;
  int nIter = 33 - ks;

  const f16* qb = q_h + ((size_t)bh * 4097 + qbase) * 40;
  for (int c = t; c < 640; c += 256)
    *(uint4*)(Ps + c * 8) = *(const uint4*)(qb + c * 8);
  if (t < 8) { Zro[t] = (f16)0; Ones[t] = (f16)1; }
  {
    float vm = (t < 65) ? kmaxp[bh * 65 + t] : 0.f;
#pragma unroll
    for (int d = 1; d < 64; d <<= 1) vm = fmaxf(vm, __shfl_xor(vm, d));
    if (lane == 0) red4[wv] = vm;
  }

  const f16* khb = k_h + ((size_t)bh * 4160 + gbase * 64) * 40;
  const f16* vtb = vt_h + (size_t)bh * 40 * 4160;
  int vrow = t >> 3, vseg = t & 7;
  uint4 rka = *(const uint4*)(khb + t * 8);
  uint4 rkb = {0, 0, 0, 0}, rvb = {0, 0, 0, 0};
  if (t < 64) rkb = *(const uint4*)(khb + (256 + t) * 8);
  uint4 rva = *(const uint4*)(vtb + vrow * 4160 + gbase * 64 + vseg * 8);
  if (t < 64) rvb = *(const uint4*)(vtb + (32 + vrow) * 4160 + gbase * 64 + vseg * 8);
  __syncthreads();

  float mk = fmaxf(fmaxf(red4[0], red4[1]), fmaxf(red4[2], red4[3]));

  half8 bq[2][2];
  float mfl[2];
#pragma unroll
  for (int nt = 0; nt < 2; ++nt) {
    int row = wv * 32 + nt * 16 + col;
    bq[nt][0] = *(half8*)(Ps + row * 40 + quad * 8);
    const f16* p1 = (quad == 0) ? (Ps + row * 40 + 32) : Zro;
    bq[nt][1] = *(half8*)p1;
    float s = 0.f;
#pragma unroll
    for (int j = 0; j < 8; ++j) {
      float a0 = (float)bq[nt][0][j], a1 = (float)bq[nt][1][j];
      s += a0 * a0 + a1 * a1;
    }
    s += __shfl_xor(s, 16);
    s += __shfl_xor(s, 32);
    mfl[nt] = sqrtf(s * mk) * c1l - 14.0f;  // Delta=14 anti-subnormal boost
  }

  f32x4 o_[2][3];
#pragma unroll
  for (int a = 0; a < 2; ++a)
#pragma unroll
    for (int b2 = 0; b2 < 3; ++b2)
#pragma unroll
      for (int r = 0; r < 4; ++r) o_[a][b2][r] = 0.f;

  f16* Pw = Ps + wv * (32 * 72);

  for (int kt = 0; kt < nIter; ++kt) {
    int bsel = kt & 1;
    int g = gbase + kt;
    *(uint4*)(&Ks[bsel][t * 8]) = rka;
    if (t < 64) *(uint4*)(&Ks[bsel][(256 + t) * 8]) = rkb;
    *(uint4*)(&Vs[bsel][vrow * 72 + vseg * 8]) = rva;
    if (t < 64) *(uint4*)(&Vs[bsel][(32 + vrow) * 72 + vseg * 8]) = rvb;
    if (kt + 1 < nIter) {
      const f16* kn = khb + (size_t)(kt + 1) * 2560;
      int k0n = (g + 1) << 6;
      rka = *(const uint4*)(kn + t * 8);
      if (t < 64) rkb = *(const uint4*)(kn + (256 + t) * 8);
      rva = *(const uint4*)(vtb + vrow * 4160 + k0n + vseg * 8);
      if (t < 64) rvb = *(const uint4*)(vtb + (32 + vrow) * 4160 + k0n + vseg * 8);
    }
    __syncthreads();

    f32x4 acc[4][2];
#pragma unroll
    for (int mt = 0; mt < 4; ++mt) {
      int row = mt * 16 + col;
      half8 ak0 = *(half8*)(&Ks[bsel][row * 40 + quad * 8]);
      const f16* pa1 = (quad == 0) ? &Ks[bsel][row * 40 + 32] : Zro;
      half8 ak1 = *(half8*)pa1;
#pragma unroll
      for (int nt = 0; nt < 2; ++nt) {
        f32x4 a; a[0] = 0.f; a[1] = 0.f; a[2] = 0.f; a[3] = 0.f;
        a = MFMA16(ak0, bq[nt][0], a);
        a = MFMA16(ak1, bq[nt][1], a);
        acc[mt][nt] = a;
      }
    }
    bool lastt = (g == 64);
#pragma unroll
    for (int mt = 0; mt < 4; ++mt)
#pragma unroll
      for (int nt = 0; nt < 2; ++nt) {
        float p[4];
#pragma unroll
        for (int r = 0; r < 4; ++r) {
          p[r] = __builtin_amdgcn_exp2f(fmaf(acc[mt][nt][r], c1l, -mfl[nt]));
          if (lastt && (mt * 16 + quad * 4 + r) != 0) p[r] = 0.f;
        }
        half2v lo = __builtin_bit_cast(half2v, __builtin_amdgcn_cvt_pkrtz(p[0], p[1]));
        half2v hi = __builtin_bit_cast(half2v, __builtin_amdgcn_cvt_pkrtz(p[2], p[3]));
        half4v pk; pk.lo = lo; pk.hi = hi;
        *(half4v*)(Pw + (nt * 16 + col) * 72 + mt * 16 + quad * 4) = pk;
      }
#pragma unroll
    for (int kk2 = 0; kk2 < 2; ++kk2) {
      half8 ap0 = *(half8*)(Pw + col * 72 + kk2 * 32 + quad * 8);
      half8 ap1 = *(half8*)(Pw + (16 + col) * 72 + kk2 * 32 + quad * 8);
#pragma unroll
      for (int nv = 0; nv < 3; ++nv) {
        int d = nv * 16 + col;
        const f16* vp = (d < 40) ? &Vs[bsel][d * 72 + kk2 * 32 + quad * 8]
                                 : ((d == 40) ? Ones : Zro);
        half8 bv = *(half8*)vp;
        o_[0][nv] = MFMA16(ap0, bv, o_[0][nv]);
        o_[1][nv] = MFMA16(ap1, bv, o_[1][nv]);
      }
    }
  }

  float* pb = pacc + (size_t)(ks * 16 + bh) * 4096 * 48;
#pragma unroll
  for (int mtq = 0; mtq < 2; ++mtq)
#pragma unroll
    for (int nv = 0; nv < 3; ++nv)
#pragma unroll
      for (int r = 0; r < 4; ++r) {
        int q = qbase + wv * 32 + mtq * 16 + quad * 4 + r;
        pb[(size_t)q * 48 + nv * 16 + col] = o_[mtq][nv][r];
      }
}

// ---------------- K3: combine K-split partials + LayerNorm + residual + upsample --------
// grid (64 y, 4 b, 2 z): block handles 32 w-rows (w = z*32..z*32+31), writes X in
// [z*64, z*64+64) of out rows 2y, 2y+1. Vectorized f32x4 pacc reads; 512 blocks (2/CU).
__global__ __launch_bounds__(256) void k_ln_out(
    const float* __restrict__ pacc, const float* __restrict__ lnw,
    const float* __restrict__ lnb, float* __restrict__ out) {
  __shared__ float g[32 * 164];
  __shared__ float linv[32 * 4];
  int y = blockIdx.x, b = blockIdx.y, z = blockIdx.z, t = threadIdx.x;
  const size_t P1 = (size_t)16 * 4096 * 48;
  int w0 = z * 32;
  if (t < 128) {
    int row = t >> 2, h = t & 3;
    size_t i0 = ((size_t)(b * 4 + h) * 4096 + y * 64 + w0 + row) * 48 + 40;
    linv[row * 4 + h] = 1.f / (pacc[i0] + pacc[P1 + i0]);
  }
  __syncthreads();
#pragma unroll
  for (int it = 0; it < 5; ++it) {
    int flat = t + it * 256;  // [0,1280) f32x4 units
    int row = flat / 40, dq = flat - row * 40;
    int h = dq / 10, d = (dq - h * 10) * 4;
    size_t idx = ((size_t)(b * 4 + h) * 4096 + y * 64 + w0 + row) * 48 + d;
    f32x4 v0 = *(const f32x4*)(pacc + idx);
    f32x4 v1 = *(const f32x4*)(pacc + P1 + idx);
    float li = linv[row * 4 + h];
    f32x4 gv;
#pragma unroll
    for (int j = 0; j < 4; ++j) gv[j] = (v0[j] + v1[j]) * li;
    *(f32x4*)(g + row * 164 + h * 40 + d) = gv;
  }
  __syncthreads();
  int row = t >> 3, part = t & 7;  // 32 rows x 8 parts x 20 cols
  float* gr = g + row * 164 + part * 20;
  float s1 = 0.f, s2 = 0.f;
#pragma unroll
  for (int j4 = 0; j4 < 5; ++j4) {
    f32x4 v = *(f32x4*)(gr + j4 * 4);
#pragma unroll
    for (int j = 0; j < 4; ++j) { s1 += v[j]; s2 += v[j] * v[j]; }
  }
  s1 += __shfl_xor(s1, 1); s1 += __shfl_xor(s1, 2); s1 += __shfl_xor(s1, 4);
  s2 += __shfl_xor(s2, 1); s2 += __shfl_xor(s2, 2); s2 += __shfl_xor(s2, 4);
  float mu = s1 * (1.f / 160.f);
  float var = s2 * (1.f / 160.f) - mu * mu;
  float inv = rsqrtf(var + 1e-5f);
  const float* lw = lnw + part * 20;
  const float* lb = lnb + part * 20;
#pragma unroll
  for (int j = 0; j < 20; ++j) {
    float v = gr[j];
    gr[j] = (v - mu) * inv * lw[j] + lb[j] + v;
  }
  __syncthreads();
  int Yo = t >> 7, xp = t & 63, cpar = (t >> 6) & 1;
  int rl = xp >> 1;
  float* ob = out + (2 * y + Yo) * 128 + z * 64 + xp;
  for (int c = cpar; c < 160; c += 2)
    ob[(size_t)(b * 160 + c) * 16384] = g[rl * 164 + c];
}

extern "C" void kernel_launch(void* const* d_in, const int* in_sizes, int n_in,
                              void* d_out, int out_size, void* d_ws, size_t ws_size,
                              hipStream_t stream) {
  const float* x   = (const float*)d_in[0];
  const float* w1  = (const float*)d_in[1];
  const float* b1  = (const float*)d_in[2];
  const float* w2  = (const float*)d_in[3];
  const float* b2  = (const float*)d_in[4];
  const float* pe  = (const float*)d_in[5];
  const float* wq  = (const float*)d_in[6];
  const float* wk  = (const float*)d_in[7];
  const float* wvp = (const float*)d_in[8];
  const float* lnw = (const float*)d_in[9];
  const float* lnb = (const float*)d_in[10];
  float* out = (float*)d_out;

  char* p = (char*)d_ws;
  f16* q_h   = (f16*)p;   p += (size_t)16 * 4097 * 40 * 2;       // 5,244,160
  f16* k_h   = (f16*)p;   p += (size_t)16 * 4160 * 40 * 2;       // 5,324,800
  f16* vt_h  = (f16*)p;   p += (size_t)16 * 40 * 4160 * 2;       // 5,324,800
  float* pacc = (float*)p; p += (size_t)2 * 16 * 4096 * 48 * 4;  // 25,165,824
  float* kmaxp = (float*)p; p += 16 * 65 * 4;                    // 4,160
  // total ~41.1 MB

  k_convqkv<<<dim3(64, 4), 256, 0, stream>>>(x, w1, b1, w2, b2, pe, wq, wk, wvp,
                                             q_h, k_h, vt_h, kmaxp);
  k_attn<<<dim3(32, 16, 2), 256, 0, stream>>>(q_h, k_h, vt_h, kmaxp, pacc);
  k_ln_out<<<dim3(64, 4, 2), 256, 0, stream>>>(pacc, lnw, lnb, out);
}